// Round 1
// baseline (4847.295 us; speedup 1.0000x reference)
//
#include <hip/hip_runtime.h>
#include <math.h>

#define B_ 32
#define T_ 512
#define I_ 512
#define H_ 1024
#define O_ 512
#define MT (B_*T_)   // 16384 rows

// ---------------------------------------------------------------------------
// GEMM: C[m][n] = bias[n] + sum_k A[m][k] * Bm[n][k]   (both row-major, "NT")
// BM=BN=128, BK=16, 256 threads, 8x8 microtile per thread.
// ---------------------------------------------------------------------------
__global__ __launch_bounds__(256)
void gemm_nt_bias(float* __restrict__ C, const float* __restrict__ A,
                  const float* __restrict__ Bm, const float* __restrict__ bias,
                  int M, int N, int K) {
  __shared__ float As[16][132];   // [k][m], +4 pad keeps 16B align, breaks stride
  __shared__ float Bs[16][132];   // [k][n]
  const int tid = threadIdx.x;
  const int bm = blockIdx.x * 128;
  const int bn = blockIdx.y * 128;
  const int lr = tid >> 2;          // 0..63  load row
  const int lc = (tid & 3) * 4;     // 0,4,8,12 (k within tile, float4)
  const int tm = (tid >> 4) * 8;    // 0..120
  const int tn = (tid & 15) * 8;

  float acc[8][8];
#pragma unroll
  for (int i = 0; i < 8; ++i)
#pragma unroll
    for (int j = 0; j < 8; ++j) acc[i][j] = 0.f;

  for (int k0 = 0; k0 < K; k0 += 16) {
    float4 a0 = *(const float4*)(A  + (size_t)(bm + lr)      * K + k0 + lc);
    float4 a1 = *(const float4*)(A  + (size_t)(bm + lr + 64) * K + k0 + lc);
    float4 b0 = *(const float4*)(Bm + (size_t)(bn + lr)      * K + k0 + lc);
    float4 b1 = *(const float4*)(Bm + (size_t)(bn + lr + 64) * K + k0 + lc);
    __syncthreads();   // previous iteration's LDS reads complete
    As[lc+0][lr]    = a0.x; As[lc+1][lr]    = a0.y; As[lc+2][lr]    = a0.z; As[lc+3][lr]    = a0.w;
    As[lc+0][lr+64] = a1.x; As[lc+1][lr+64] = a1.y; As[lc+2][lr+64] = a1.z; As[lc+3][lr+64] = a1.w;
    Bs[lc+0][lr]    = b0.x; Bs[lc+1][lr]    = b0.y; Bs[lc+2][lr]    = b0.z; Bs[lc+3][lr]    = b0.w;
    Bs[lc+0][lr+64] = b1.x; Bs[lc+1][lr+64] = b1.y; Bs[lc+2][lr+64] = b1.z; Bs[lc+3][lr+64] = b1.w;
    __syncthreads();
#pragma unroll
    for (int k = 0; k < 16; ++k) {
      float a[8], b[8];
      *(float4*)&a[0] = *(const float4*)&As[k][tm];
      *(float4*)&a[4] = *(const float4*)&As[k][tm + 4];
      *(float4*)&b[0] = *(const float4*)&Bs[k][tn];
      *(float4*)&b[4] = *(const float4*)&Bs[k][tn + 4];
#pragma unroll
      for (int i = 0; i < 8; ++i)
#pragma unroll
        for (int j = 0; j < 8; ++j) acc[i][j] += a[i] * b[j];
    }
  }

  float bv[8];
#pragma unroll
  for (int j = 0; j < 8; ++j) bv[j] = bias[bn + tn + j];
#pragma unroll
  for (int i = 0; i < 8; ++i) {
    float* crow = C + (size_t)(bm + tm + i) * N + bn + tn;
    float4 o0 = {acc[i][0]+bv[0], acc[i][1]+bv[1], acc[i][2]+bv[2], acc[i][3]+bv[3]};
    float4 o1 = {acc[i][4]+bv[4], acc[i][5]+bv[5], acc[i][6]+bv[6], acc[i][7]+bv[7]};
    *(float4*)(crow)     = o0;
    *(float4*)(crow + 4) = o1;
  }
}

// ---------------------------------------------------------------------------
// One recurrence step, in-place on z:
//   z[b][t][j] = tanh( z[b][t][j](=pre) + sum_k h_prev[b][k]*W_hh[j][k] + b_hh[j] )
// h_prev = h0 (t==0) else z[b][t-1][:].
// Grid 256 blocks: block owns 4 output columns j. Thread (b = tid&31, s = tid>>5)
// covers k-groups g with g%8==s (8-way k-split), LDS reduce at the end.
// ---------------------------------------------------------------------------
__global__ __launch_bounds__(256)
void rnn_step(float* __restrict__ z, const float* __restrict__ h0,
              const float* __restrict__ Whh, const float* __restrict__ bhh,
              int t) {
  __shared__ float Ws[4][1032];      // 4 full W_hh rows (1024 + 8 pad words)
  __shared__ float hs[32][132];      // h tile: 32 b x 128 k (+4 pad)
  __shared__ float red[8 * 32 * 4];  // k-split partials

  const int tid = threadIdx.x;
  const int j0 = blockIdx.x * 4;

  // stage W rows (coalesced, once per launch)
  {
    const int j  = tid >> 6;        // 0..3
    const int c4 = tid & 63;        // 0..63
    const float4* src = (const float4*)(Whh + (size_t)(j0 + j) * H_);
#pragma unroll
    for (int i = 0; i < 4; ++i) {
      float4 v = src[c4 + 64 * i];
      *(float4*)&Ws[j][(c4 + 64 * i) * 4] = v;
    }
  }

  const float* hbase;
  size_t hstride;
  if (t == 0) { hbase = h0;                     hstride = H_; }
  else        { hbase = z + (size_t)(t-1) * H_; hstride = (size_t)T_ * H_; }

  const int b = tid & 31;
  const int s = tid >> 5;          // 0..7
  const int srow = tid >> 3;       // staging: row 0..31
  const int sc4  = tid & 7;        // staging: 8 float4-cols per row pass

  float partial[4] = {0.f, 0.f, 0.f, 0.f};

  for (int kt = 0; kt < H_; kt += 128) {
    __syncthreads();
    // stage h tile [32][128] coalesced
    const float* hsrc = hbase + (size_t)srow * hstride + kt;
#pragma unroll
    for (int i = 0; i < 4; ++i) {
      float4 v = *(const float4*)(hsrc + (sc4 + 8 * i) * 4);
      *(float4*)&hs[srow][(sc4 + 8 * i) * 4] = v;
    }
    __syncthreads();
#pragma unroll
    for (int m = 0; m < 4; ++m) {
      const int g  = m * 8 + s;          // 0..31 column-group in tile
      float4 hv = *(const float4*)&hs[b][g * 4];
      const int kw = kt + g * 4;
#pragma unroll
      for (int j = 0; j < 4; ++j) {
        float4 wv = *(const float4*)&Ws[j][kw];
        partial[j] += hv.x*wv.x + hv.y*wv.y + hv.z*wv.z + hv.w*wv.w;
      }
    }
  }

#pragma unroll
  for (int j = 0; j < 4; ++j) red[(s * 32 + b) * 4 + j] = partial[j];
  __syncthreads();

  if (tid < 128) {
    const int rb = tid >> 2;
    const int rj = tid & 3;
    float v = 0.f;
#pragma unroll
    for (int ss = 0; ss < 8; ++ss) v += red[(ss * 32 + rb) * 4 + rj];
    const size_t idx = (size_t)rb * T_ * H_ + (size_t)t * H_ + j0 + rj;
    v += z[idx] + bhh[j0 + rj];          // + pre + bias
    z[idx] = tanhf(v);
  }
}

// ---------------------------------------------------------------------------
// Row softmax in place over O_=512 columns. One wave per row.
// ---------------------------------------------------------------------------
__global__ __launch_bounds__(256)
void softmax_rows(float* __restrict__ P) {
  const int row  = blockIdx.x * 4 + (threadIdx.x >> 6);
  const int lane = threadIdx.x & 63;
  float* p = P + (size_t)row * O_;
  float4 v0 = *(const float4*)(p + lane * 4);
  float4 v1 = *(const float4*)(p + 256 + lane * 4);

  float m = fmaxf(fmaxf(fmaxf(v0.x, v0.y), fmaxf(v0.z, v0.w)),
                  fmaxf(fmaxf(v1.x, v1.y), fmaxf(v1.z, v1.w)));
#pragma unroll
  for (int off = 32; off; off >>= 1) m = fmaxf(m, __shfl_xor(m, off, 64));

  v0.x = __expf(v0.x - m); v0.y = __expf(v0.y - m);
  v0.z = __expf(v0.z - m); v0.w = __expf(v0.w - m);
  v1.x = __expf(v1.x - m); v1.y = __expf(v1.y - m);
  v1.z = __expf(v1.z - m); v1.w = __expf(v1.w - m);

  float s = v0.x + v0.y + v0.z + v0.w + v1.x + v1.y + v1.z + v1.w;
#pragma unroll
  for (int off = 32; off; off >>= 1) s += __shfl_xor(s, off, 64);
  const float inv = 1.f / s;

  v0.x *= inv; v0.y *= inv; v0.z *= inv; v0.w *= inv;
  v1.x *= inv; v1.y *= inv; v1.z *= inv; v1.w *= inv;
  *(float4*)(p + lane * 4)       = v0;
  *(float4*)(p + 256 + lane * 4) = v1;
}

// ---------------------------------------------------------------------------
extern "C" void kernel_launch(void* const* d_in, const int* in_sizes, int n_in,
                              void* d_out, int out_size, void* d_ws, size_t ws_size,
                              hipStream_t stream) {
  const float* x    = (const float*)d_in[0];   // [B,T,I]
  const float* h0   = (const float*)d_in[1];   // [1,B,H]
  const float* Wih  = (const float*)d_in[2];   // [H,I]
  const float* Whh  = (const float*)d_in[3];   // [H,H]
  const float* bih  = (const float*)d_in[4];   // [H]
  const float* bhh  = (const float*)d_in[5];   // [H]
  const float* Wout = (const float*)d_in[6];   // [O,H]
  const float* bout = (const float*)d_in[7];   // [O]

  float* outp = (float*)d_out;                       // [B,T,O]
  float* z    = (float*)d_out + (size_t)MT * O_;     // [B,T,H]

  // Phase 1: pre = x @ W_ih^T + b_ih, written directly into z region
  gemm_nt_bias<<<dim3(MT / 128, H_ / 128), 256, 0, stream>>>(z, x, Wih, bih, MT, H_, I_);

  // Phase 2: 512 sequential recurrence steps, in place on z
  for (int t = 0; t < T_; ++t)
    rnn_step<<<dim3(H_ / 4), 256, 0, stream>>>(z, h0, Whh, bhh, t);

  // Phase 3: logits = z @ W_out^T + b_out, then row softmax in place
  gemm_nt_bias<<<dim3(MT / 128, O_ / 128), 256, 0, stream>>>(outp, z, Wout, bout, MT, O_, H_);
  softmax_rows<<<dim3(MT / 4), 256, 0, stream>>>(outp);
}